// Round 15
// baseline (796.350 us; speedup 1.0000x reference)
//
#include <hip/hip_runtime.h>
#include <hip/hip_bf16.h>
#include <stdint.h>

// ---------------------------------------------------------------------------
// getGRU restructured:
//   inp_t = h_t @ W_d + b_d  (t>=1)  =>  gx_t = h_t @ (W_d W_x) + bconst
//   per-frame: ONE GEMM [256 x 2048] @ WC^T, WC rows = [r|z|xn|hn] (8192)
//   out_t for all t: ONE batched GEMM Hs[8192 x 2048] @ W_d + b_d (+BN stats),
//   then one-pass BN apply.
// Round 15: (a) gemm_wc reverted to r8's 512-thr form (r14's 256-thr port
// regressed 45->76 us).  (b) frame_kernel -> 2 blocks/CU: 256 thr, 32-row
// tiles, grid (64,8), 80 KB LDS (4-buf distance-2 unchanged) -- co-resident
// block absorbs barrier/L2-miss stalls (m114 mechanism, never applied here).
// ---------------------------------------------------------------------------

typedef __attribute__((ext_vector_type(8))) _Float16 half8;
typedef __attribute__((ext_vector_type(4))) float f32x4;
typedef __attribute__((ext_vector_type(16))) float f32x16;
typedef unsigned short u16;

#define GLB_CAST(p) ((const __attribute__((address_space(1))) void*)(p))
#define LDS_CAST(p) ((__attribute__((address_space(3))) void*)(p))

static __device__ __forceinline__ void gload_lds16(const void* g, void* l) {
  __builtin_amdgcn_global_load_lds(GLB_CAST(g), LDS_CAST(l), 16, 0, 0);
}
static __device__ __forceinline__ u16 f2h(float f) {
  _Float16 h = (_Float16)f;
  return __builtin_bit_cast(u16, h);
}
static __device__ __forceinline__ float h2f(u16 u) {
  _Float16 h = __builtin_bit_cast(_Float16, u);
  return (float)h;
}

// ---------------------------------------------------------------------------
// Tiled transpose + f32 -> f16:  dst[j*dst_ld + k] = f16(src[k*src_ld + j0 + j])
// ---------------------------------------------------------------------------
__global__ __launch_bounds__(256) void transpose_conv(
    const float* __restrict__ src, int src_ld, int j0,
    u16* __restrict__ dst, int dst_ld)
{
  __shared__ float tile[32][33];
  const int kt = blockIdx.y * 32, jt = blockIdx.x * 32;
  const int tr = threadIdx.x >> 5, tc = threadIdx.x & 31;
#pragma unroll
  for (int r = 0; r < 4; r++)
    tile[tr + r * 8][tc] = src[(size_t)(kt + tr + r * 8) * src_ld + j0 + jt + tc];
  __syncthreads();
#pragma unroll
  for (int r = 0; r < 4; r++)
    dst[(size_t)(jt + tr + r * 8) * dst_ld + kt + tc] = f2h(tile[tc][tr + r * 8]);
}

__global__ __launch_bounds__(256) void convert_f2h(
    const float* __restrict__ src, u16* __restrict__ dst)
{
  const int i = (blockIdx.x * 256 + threadIdx.x) * 4;
  float4 v = *(const float4*)(src + i);
  dst[i + 0] = f2h(v.x); dst[i + 1] = f2h(v.y);
  dst[i + 2] = f2h(v.z); dst[i + 3] = f2h(v.w);
}

// bconst[j] = b_x[j] + sum_k b_d[k] * XT[j][k]
__global__ __launch_bounds__(256) void bconst_kernel(
    const float* __restrict__ bx, const float* __restrict__ bd,
    const u16* __restrict__ XT, float* __restrict__ bc)
{
  __shared__ float sbd[1024];
  const int tid = threadIdx.x;
  for (int i = tid; i < 1024; i += 256) sbd[i] = bd[i];
  __syncthreads();
  const int j = blockIdx.x * 256 + tid;
  const u16* row = XT + (size_t)j * 1024;
  float s = bx[j];
  for (int k = 0; k < 1024; k += 8) {
    half8 v = *(const half8*)(row + k);
#pragma unroll
    for (int u = 0; u < 8; u++) s += sbd[k + u] * (float)v[u];
  }
  bc[j] = s;
}

// ---------------------------------------------------------------------------
// gemm_wc (r8 version): WC[m][n] = sum_k XT[m][k]*Wd16[n][k] (+HT for m<4096).
// 128x128 tile, 512 thr (8 waves = 4rw x 2jw), 2-buf counted-vmcnt pipeline.
// grid (48, 16) m-fastest.  K = 1024.
// ---------------------------------------------------------------------------
__global__ __launch_bounds__(512) void gemm_wc(
    const u16* __restrict__ A, const u16* __restrict__ Bm,
    const u16* __restrict__ HT, u16* __restrict__ Cw)
{
  __shared__ __attribute__((aligned(16))) u16 a_lds[2][128 * 64];
  __shared__ __attribute__((aligned(16))) u16 b_lds[2][128 * 64];
  const int tid = threadIdx.x, w = tid >> 6, l = tid & 63;
  const int rw = w >> 1, jw = w & 1;
  const int m0 = blockIdx.x * 128, n0 = blockIdx.y * 128;
  f32x4 acc[2][4] = {};

  const u16 *asrc[2], *bsrc[2];
#pragma unroll
  for (int rnd = 0; rnd < 2; rnd++) {
    int flat = rnd * 512 + tid;
    int row = flat >> 3, gch = (flat & 7) ^ (row & 7);
    asrc[rnd] = A + (size_t)(m0 + row) * 1024 + gch * 8;
    bsrc[rnd] = Bm + (size_t)(n0 + row) * 1024 + gch * 8;
  }
  auto stage = [&](int buf, int kk) {   // 4 gloads/thread
#pragma unroll
    for (int rnd = 0; rnd < 2; rnd++) {
      int flat = rnd * 512 + tid;
      gload_lds16(asrc[rnd] + kk, a_lds[buf] + flat * 8);
      gload_lds16(bsrc[rnd] + kk, b_lds[buf] + flat * 8);
    }
  };
  auto compute = [&](int buf) {
    __builtin_amdgcn_s_setprio(1);
#pragma unroll
    for (int kh = 0; kh < 2; kh++) {
      const int c = kh * 4 + (l >> 4);
      half8 a[2], b[4];
#pragma unroll
      for (int mf = 0; mf < 2; mf++) {
        int arow = rw * 32 + mf * 16 + (l & 15);
        a[mf] = *(const half8*)(a_lds[buf] + (arow * 8 + (c ^ (arow & 7))) * 8);
      }
#pragma unroll
      for (int nf = 0; nf < 4; nf++) {
        int brow = jw * 64 + nf * 16 + (l & 15);
        b[nf] = *(const half8*)(b_lds[buf] + (brow * 8 + (c ^ (brow & 7))) * 8);
      }
#pragma unroll
      for (int mf = 0; mf < 2; mf++)
#pragma unroll
        for (int nf = 0; nf < 4; nf++)
          acc[mf][nf] = __builtin_amdgcn_mfma_f32_16x16x32_f16(a[mf], b[nf], acc[mf][nf], 0, 0, 0);
    }
    __builtin_amdgcn_s_setprio(0);
  };

  stage(0, 0);
#pragma unroll 1
  for (int t = 0; t < 16; ++t) {
    if (t < 15) {
      stage((t + 1) & 1, (t + 1) * 64);
      asm volatile("s_waitcnt vmcnt(4)\ns_barrier" ::: "memory");
    } else {
      asm volatile("s_waitcnt vmcnt(0)\ns_barrier" ::: "memory");
    }
    compute(t & 1);
    asm volatile("s_barrier" ::: "memory");
  }

#pragma unroll
  for (int mf = 0; mf < 2; mf++)
#pragma unroll
    for (int nf = 0; nf < 4; nf++) {
      const int n = n0 + jw * 64 + nf * 16 + (l & 15);
#pragma unroll
      for (int i = 0; i < 4; i++) {
        const int m = m0 + rw * 32 + mf * 16 + (l >> 4) * 4 + i;
        float v = acc[mf][nf][i];
        if (m < 4096) v += h2f(HT[(size_t)m * 2048 + n]);
        Cw[(size_t)m * 2048 + n] = f2h(v);
      }
    }
}

// ---------------------------------------------------------------------------
// gemm_out: O[m][n] = sum_k Hs[m][k]*DT[n][k] + bd[n]; fused BN partial stats.
// 128x128 tile, 256 thr (4 waves = 2mw x 2nw, 64x64 wave tiles, 32x32x16),
// 2-buf counted-vmcnt, 64KB LDS -> 2 blocks/CU.  grid (64, 8) m-fastest.
// ---------------------------------------------------------------------------
__global__ __launch_bounds__(256) void gemm_out(
    const u16* __restrict__ A, const u16* __restrict__ Bm,
    const float* __restrict__ bd, float* __restrict__ O,
    float* __restrict__ bnsum, float* __restrict__ bnsq)
{
  __shared__ __attribute__((aligned(16))) u16 a_lds[2][128 * 64];  // 16KB each
  __shared__ __attribute__((aligned(16))) u16 b_lds[2][128 * 64];
  const int tid = threadIdx.x, w = tid >> 6, l = tid & 63;
  const int mw = w >> 1, nw = w & 1;
  const int m0 = blockIdx.x * 128, n0 = blockIdx.y * 128;
  const int lr = l & 31, lh = l >> 5;
  f32x16 acc[2][2] = {};

  const u16 *asrc[4], *bsrc[4];
#pragma unroll
  for (int rnd = 0; rnd < 4; rnd++) {
    int flat = rnd * 256 + tid;
    int row = flat >> 3, gch = (flat & 7) ^ (row & 7);
    asrc[rnd] = A + (size_t)(m0 + row) * 2048 + gch * 8;
    bsrc[rnd] = Bm + (size_t)(n0 + row) * 2048 + gch * 8;
  }
  auto stage = [&](int buf, int kk) {  // 8 gloads/thread
#pragma unroll
    for (int rnd = 0; rnd < 4; rnd++) {
      gload_lds16(asrc[rnd] + kk, a_lds[buf] + (rnd * 256 + tid) * 8);
      gload_lds16(bsrc[rnd] + kk, b_lds[buf] + (rnd * 256 + tid) * 8);
    }
  };
  auto compute = [&](int buf) {
    __builtin_amdgcn_s_setprio(1);
#pragma unroll
    for (int ks = 0; ks < 4; ks++) {       // four K16 slices of the K64 step
      const int c = ks * 2 + lh;
      half8 a[2], b[2];
#pragma unroll
      for (int mf = 0; mf < 2; mf++) {
        int ar = mw * 64 + mf * 32 + lr;
        a[mf] = *(const half8*)(a_lds[buf] + (ar * 8 + (c ^ (ar & 7))) * 8);
      }
#pragma unroll
      for (int nf = 0; nf < 2; nf++) {
        int br = nw * 64 + nf * 32 + lr;
        b[nf] = *(const half8*)(b_lds[buf] + (br * 8 + (c ^ (br & 7))) * 8);
      }
#pragma unroll
      for (int mf = 0; mf < 2; mf++)
#pragma unroll
        for (int nf = 0; nf < 2; nf++)
          acc[mf][nf] = __builtin_amdgcn_mfma_f32_32x32x16_f16(a[mf], b[nf], acc[mf][nf], 0, 0, 0);
    }
    __builtin_amdgcn_s_setprio(0);
  };

  stage(0, 0);
#pragma unroll 1
  for (int t = 0; t < 32; ++t) {
    if (t < 31) {
      stage((t + 1) & 1, (t + 1) * 64);
      asm volatile("s_waitcnt vmcnt(8)\ns_barrier" ::: "memory");
    } else {
      asm volatile("s_waitcnt vmcnt(0)\ns_barrier" ::: "memory");
    }
    compute(t & 1);
    asm volatile("s_barrier" ::: "memory");
  }

  // epilogue: C/D row within 32 = (reg&3) + 8*(reg>>2) + 4*lh, col = lr
  const int fr = m0 >> 8;   // frame index (2 m-tiles per frame)
#pragma unroll
  for (int nf = 0; nf < 2; nf++) {
    const int n = n0 + nw * 64 + nf * 32 + lr;
    const float bb = bd[n];
    float s = 0.f, q = 0.f;
#pragma unroll
    for (int mf = 0; mf < 2; mf++)
#pragma unroll
      for (int reg = 0; reg < 16; reg++) {
        const int m = m0 + mw * 64 + mf * 32 + (reg & 3) + 8 * (reg >> 2) + 4 * lh;
        float v = acc[mf][nf][reg] + bb;
        O[(size_t)m * 1024 + n] = v;
        s += v; q += v * v;
      }
    s += __shfl_xor(s, 32, 64); q += __shfl_xor(q, 32, 64);
    if (lh == 0) {
      atomicAdd(&bnsum[fr * 1024 + n], s);
      atomicAdd(&bnsq[fr * 1024 + n], q);
    }
  }
}

// ---------------------------------------------------------------------------
// Frame 0: gates from x @ W_x only (h=0).  grid (64,4), 512 thr, dbuf.
// ---------------------------------------------------------------------------
__global__ __launch_bounds__(512) void frame0_kernel(
    const u16* __restrict__ x16, const u16* __restrict__ XT,
    const float* __restrict__ bx, const float* __restrict__ bh,
    float* __restrict__ h32out, u16* __restrict__ hout16)
{
  __shared__ __attribute__((aligned(16))) u16 a_lds[2][64 * 64];
  __shared__ __attribute__((aligned(16))) u16 b_lds[2][96 * 64];
  const int tid = threadIdx.x, w = tid >> 6, l = tid & 63;
  const int rw = w >> 1, jw = w & 1;
  const int jt = blockIdx.x, r0 = blockIdx.y * 64;
  f32x4 acc[3] = {};

  const int ar = tid >> 3;
  const int agch = (tid & 7) ^ (ar & 7);
  const u16* asrc = x16 + (size_t)(r0 + ar) * 1024 + agch * 8;
  const u16* bsrc0;
  const u16* bsrc1;
  {
    int row0 = tid >> 3, gch0 = (tid & 7) ^ (row0 & 7);
    bsrc0 = XT + (size_t)((row0 >> 5) * 2048 + jt * 32 + (row0 & 31)) * 1024 + gch0 * 8;
    int flat = 512 + tid;
    int row1 = flat >> 3, gch1 = (flat & 7) ^ (row1 & 7);
    bsrc1 = XT + (size_t)((row1 >> 5) * 2048 + jt * 32 + (row1 & 31)) * 1024 + gch1 * 8;
  }
  auto stage = [&](int buf, int kk) {
    gload_lds16(asrc + kk, a_lds[buf] + tid * 8);
    gload_lds16(bsrc0 + kk, b_lds[buf] + tid * 8);
    if (512 + tid < 768)
      gload_lds16(bsrc1 + kk, b_lds[buf] + (512 + tid) * 8);
  };

  stage(0, 0);
  __syncthreads();
  int cur = 0;
  for (int t = 0; t < 16; ++t) {
    if (t < 15) stage(cur ^ 1, (t + 1) * 64);
    const int arow = rw * 16 + (l & 15);
#pragma unroll
    for (int kh = 0; kh < 2; kh++) {
      int apch = (kh * 4 + (l >> 4)) ^ (arow & 7);
      half8 a = *(const half8*)(a_lds[cur] + arow * 64 + apch * 8);
#pragma unroll
      for (int s = 0; s < 3; s++) {
        int brow = s * 32 + jw * 16 + (l & 15);
        int bpch = (kh * 4 + (l >> 4)) ^ (brow & 7);
        half8 bf = *(const half8*)(b_lds[cur] + brow * 64 + bpch * 8);
        acc[s] = __builtin_amdgcn_mfma_f32_16x16x32_f16(a, bf, acc[s], 0, 0, 0);
      }
    }
    __syncthreads();
    cur ^= 1;
  }

  const int j = jt * 32 + jw * 16 + (l & 15);
  const float cR = bx[j] + bh[j];
  const float cZ = bx[2048 + j] + bh[2048 + j];
  const float cX = bx[4096 + j];
  const float hn0 = bh[4096 + j];
#pragma unroll
  for (int i = 0; i < 4; i++) {
    const int b = r0 + rw * 16 + (l >> 4) * 4 + i;
    float r = 1.f / (1.f + __expf(-(acc[0][i] + cR)));
    float z = 1.f / (1.f + __expf(-(acc[1][i] + cZ)));
    float n = tanhf(acc[2][i] + cX + r * hn0);
    float hv = (1.f - z) * n;
    h32out[b * 2048 + j] = hv;
    hout16[b * 2048 + j] = f2h(hv);
  }
}

// ---------------------------------------------------------------------------
// Frames 1..31: gates = h @ WC^T (+consts), GRU update.
// grid (64,8): jt, 32-row block.  256 thr = 4 waves = 2cw x 2kw.  Wave tile
// 32 rows x 64 cols (2 nf of 32, mfma 32x32x16); kw = K32 slice of K64 step.
// 4-buf distance-2 counted-vmcnt pipeline; 80 KB LDS -> 2 blocks/CU.
// End: 2-way kw reduction + full gate exchange via 32 KB aliased LDS:
//   write  xch[(cw*2+kw)*2048 + (nf*4+q)*256 + l*4 + d]  (regs 4q+d)
//   value stored = gate sec=cw*2+nf, row=(d)+8q+4*(l>>5), j=l&31
//   read (thread w',l wants row=8w'+4lh+d, j=lr, sec, sum kw):
//     q=w', lane=l -> f32x4 at [(sec>>1)*2+kw]*2048 + ((sec&1)*4+w')*256 + l*4
// C/D: col = l&31, row = (reg&3)+8*(reg>>2)+4*(l>>5)  [m74/m101].
// ---------------------------------------------------------------------------
__global__ __launch_bounds__(256) void frame_kernel(
    const u16* __restrict__ hin16,   // Hs[t-1]  [256][2048]
    const u16* __restrict__ WC,      // [8192][2048]
    const float* __restrict__ bc, const float* __restrict__ bh,
    const float* __restrict__ h32in, float* __restrict__ h32out,
    u16* __restrict__ hout16)        // Hs[t]
{
  __shared__ __attribute__((aligned(16))) char raw[81920];  // 80 KB
  u16* aL = (u16*)raw;                  // 4 bufs x 4KB  = 16 KB
  u16* bL = (u16*)(raw + 16384);        // 4 bufs x 16KB = 64 KB
  float* xch = (float*)raw;             // 32 KB exchange (aliased)
  const int tid = threadIdx.x, w = tid >> 6, l = tid & 63;
  const int cw = w & 1, kw = w >> 1;    // col-half, K32 slice
  const int jt = blockIdx.x, r0 = blockIdx.y * 32;
  const int lr = l & 31, lh = l >> 5;

  f32x16 acc[2] = {};                   // [nf]

  const u16* asrc;                      // 1 load/thread (rows 0..31)
  {
    int row = tid >> 3, gch = (tid & 7) ^ (row & 7);
    asrc = hin16 + (size_t)(r0 + row) * 2048 + gch * 8;
  }
  const u16* bsrc[4];                   // 4 loads/thread (rows 0..127)
#pragma unroll
  for (int rnd = 0; rnd < 4; rnd++) {
    int flat = rnd * 256 + tid;
    int row = flat >> 3, gch = (flat & 7) ^ (row & 7);
    int sec = row >> 5, jr = row & 31;
    bsrc[rnd] = WC + (size_t)(sec * 2048 + jt * 32 + jr) * 2048 + gch * 8;
  }
  auto stage = [&](int buf, int step) {   // 5 gloads/thread (uniform)
    const int kk = step * 64;
    gload_lds16(asrc + kk, aL + buf * 2048 + tid * 8);
#pragma unroll
    for (int rnd = 0; rnd < 4; rnd++)
      gload_lds16(bsrc[rnd] + kk, bL + buf * 8192 + (rnd * 256 + tid) * 8);
  };
  auto compute = [&](int buf) {
    __builtin_amdgcn_s_setprio(1);
#pragma unroll
    for (int ks = 0; ks < 2; ks++) {
      const int c = (kw * 2 + ks) * 2 + lh;   // 16B chunk 0..7
      half8 a = *(const half8*)(aL + buf * 2048 + (lr * 8 + (c ^ (lr & 7))) * 8);
#pragma unroll
      for (int nf = 0; nf < 2; nf++) {
        int br = (cw * 2 + nf) * 32 + lr;
        half8 b = *(const half8*)(bL + buf * 8192 + (br * 8 + (c ^ (br & 7))) * 8);
        acc[nf] = __builtin_amdgcn_mfma_f32_32x32x16_f16(a, b, acc[nf], 0, 0, 0);
      }
    }
    __builtin_amdgcn_s_setprio(0);
  };

  stage(0, 0);
  stage(1, 1);
#pragma unroll 1
  for (int t = 0; t < 30; ++t) {
    stage((t + 2) & 3, t + 2);
    asm volatile("s_waitcnt vmcnt(10)\ns_barrier" ::: "memory");
    compute(t & 3);
  }
  asm volatile("s_waitcnt vmcnt(5)\ns_barrier" ::: "memory");
  compute(2);
  asm volatile("s_waitcnt vmcnt(0)\ns_barrier" ::: "memory");
  compute(3);

  // ---- kw reduction + gate exchange ----
  __syncthreads();   // drain all LDS reads before aliasing bufs as xch
#pragma unroll
  for (int nf = 0; nf < 2; nf++)
#pragma unroll
    for (int q = 0; q < 4; q++) {
      f32x4 v;
#pragma unroll
      for (int d = 0; d < 4; d++) v[d] = acc[nf][q * 4 + d];
      *(f32x4*)(xch + (cw * 2 + kw) * 2048 + (nf * 4 + q) * 256 + l * 4) = v;
    }
  __syncthreads();

  f32x4 g[4];   // R, Z, Xn, Hn for rows 8w + 4lh + d, col jt*32 + lr
#pragma unroll
  for (int sec = 0; sec < 4; sec++) {
    f32x4 s = {};
#pragma unroll
    for (int k2 = 0; k2 < 2; k2++)
      s += *(const f32x4*)(xch + ((sec >> 1) * 2 + k2) * 2048 +
                           ((sec & 1) * 4 + w) * 256 + l * 4);
    g[sec] = s;
  }
  const int j = jt * 32 + lr;
  const float cR = bc[j] + bh[j];
  const float cZ = bc[2048 + j] + bh[2048 + j];
  const float cX = bc[4096 + j];
  const float cH = bh[4096 + j];
#pragma unroll
  for (int d = 0; d < 4; d++) {
    const int bb = r0 + 8 * w + 4 * lh + d;
    float rg = 1.f / (1.f + __expf(-(g[0][d] + cR)));
    float zg = 1.f / (1.f + __expf(-(g[1][d] + cZ)));
    float ng = tanhf(g[2][d] + cX + rg * (g[3][d] + cH));
    float hp = h32in[bb * 2048 + j];
    float hv = (1.f - zg) * ng + zg * hp;
    h32out[bb * 2048 + j] = hv;
    hout16[bb * 2048 + j] = f2h(hv);
  }
}

// ---------------------------------------------------------------------------
// BN apply (stats precomputed): one pass over d_out.  grid (32,4), 256 thr.
// ---------------------------------------------------------------------------
__global__ __launch_bounds__(256) void bn_apply(
    float* __restrict__ O, const float* __restrict__ bnsum,
    const float* __restrict__ bnsq, const float* __restrict__ gamma,
    const float* __restrict__ beta)
{
  const int t = blockIdx.x, j = blockIdx.y * 256 + threadIdx.x;
  const float mean = bnsum[t * 1024 + j] * (1.f / 256.f);
  const float var = bnsq[t * 1024 + j] * (1.f / 256.f) - mean * mean;
  const float inv = rsqrtf(var + 1e-5f);
  const float g = gamma[j] * inv, be = beta[j];
  const size_t base = (size_t)t * 256 * 1024 + j;
  for (int b = 0; b < 256; b++) {
    const size_t idx = base + (size_t)b * 1024;
    O[idx] = (O[idx] - mean) * g + be;
  }
}

// ---------------------------------------------------------------------------
extern "C" void kernel_launch(void* const* d_in, const int* in_sizes, int n_in,
                              void* d_out, int out_size, void* d_ws, size_t ws_size,
                              hipStream_t stream)
{
  (void)in_sizes; (void)n_in; (void)out_size; (void)ws_size;
  const float* x  = (const float*)d_in[0];
  const float* Wx = (const float*)d_in[1];
  const float* Wh = (const float*)d_in[2];
  const float* bx = (const float*)d_in[3];
  const float* bh = (const float*)d_in[4];
  const float* Wd = (const float*)d_in[5];
  const float* bd = (const float*)d_in[6];
  const float* gamma = (const float*)d_in[7];
  const float* beta  = (const float*)d_in[8];

  char* p = (char*)d_ws;
  u16* XT  = (u16*)p;  p += (size_t)6144 * 1024 * 2;   // W_x^T  [6144][1024]
  u16* WC  = (u16*)p;  p += (size_t)8192 * 2048 * 2;   // combined weights
  u16* DT  = (u16*)p;  p += (size_t)1024 * 2048 * 2;   // W_d^T  [1024][2048]
  float* h32a = (float*)p; p += (size_t)256 * 2048 * 4;
  float* h32b = (float*)p; p += (size_t)256 * 2048 * 4;
  u16* x16 = (u16*)p;  p += (size_t)256 * 1024 * 2;
  float* bc = (float*)p; p += (size_t)6144 * 4;
  float* bnsum = (float*)p; p += (size_t)32 * 1024 * 4;
  float* bnsq  = (float*)p; p += (size_t)32 * 1024 * 4;
  // aliased region: HT+Wd16 (setup only) overlaid by Hs (frame0 onward)
  u16* Hs   = (u16*)p;                                  // [32][256][2048]
  u16* HT   = (u16*)p;                                  // [4096][2048]
  u16* Wd16 = (u16*)(p + (size_t)4096 * 2048 * 2);      // [2048][1024]

  const size_t BH = (size_t)256 * 2048;

  // --- setup ---------------------------------------------------------------
  transpose_conv<<<dim3(192, 32), 256, 0, stream>>>(Wx, 6144, 0, XT, 1024);
  transpose_conv<<<dim3(128, 64), 256, 0, stream>>>(Wh, 6144, 0, HT, 2048);
  transpose_conv<<<dim3(64, 64), 256, 0, stream>>>(Wh, 6144, 4096,
                                                   WC + (size_t)6144 * 2048, 2048);
  transpose_conv<<<dim3(32, 64), 256, 0, stream>>>(Wd, 1024, 0, DT, 2048);
  convert_f2h<<<2048, 256, 0, stream>>>(Wd, Wd16);
  convert_f2h<<<256, 256, 0, stream>>>(x, x16);
  bconst_kernel<<<24, 256, 0, stream>>>(bx, bd, XT, bc);
  hipMemsetAsync(bnsum, 0, (size_t)2 * 32 * 1024 * 4, stream);
  // WC[0:6144] = XT @ Wd16^T (+HT for rows<4096)
  gemm_wc<<<dim3(48, 16), 512, 0, stream>>>(XT, Wd16, HT, WC);

  // --- recurrence ----------------------------------------------------------
  frame0_kernel<<<dim3(64, 4), 512, 0, stream>>>(x16, XT, bx, bh, h32a, Hs);
  for (int t = 1; t < 32; t++) {
    const float* hin32 = (t & 1) ? h32a : h32b;
    float* hout32      = (t & 1) ? h32b : h32a;
    frame_kernel<<<dim3(64, 8), 256, 0, stream>>>(
        Hs + (size_t)(t - 1) * BH, WC, bc, bh, hin32, hout32, Hs + (size_t)t * BH);
  }

  // --- all 32 output frames in one GEMM (+BN stats), then BN apply ---------
  gemm_out<<<dim3(64, 8), 256, 0, stream>>>(Hs, DT, bd, (float*)d_out, bnsum, bnsq);
  bn_apply<<<dim3(32, 4), 256, 0, stream>>>((float*)d_out, bnsum, bnsq, gamma, beta);
}

// Round 16
// 699.103 us; speedup vs baseline: 1.1391x; 1.1391x over previous
//
#include <hip/hip_runtime.h>
#include <hip/hip_bf16.h>
#include <stdint.h>

// ---------------------------------------------------------------------------
// getGRU restructured:
//   inp_t = h_t @ W_d + b_d  (t>=1)  =>  gx_t = h_t @ (W_d W_x) + bconst
//   per-frame: ONE GEMM [256 x 2048] @ WC^T, WC rows = [r|z|xn|hn] (8192)
//   out_t for all t: ONE batched GEMM Hs[8192 x 2048] @ W_d + b_d (+BN stats),
//   then one-pass BN apply.
// Round 16: exact restore of the round-8 configuration -- the measured
// optimum (700 us).  All later variants (persistent grid-barrier kernels,
// coherence/NT cache policies, deeper prefetch, occupancy splits) measured
// 722-973 us; the frame kernel is pinned by the structural WC-over-L2
// working-set thrash (4.2 MB/XCD vs 4.0 MB L2, invariant r10-r13).
// ---------------------------------------------------------------------------

typedef __attribute__((ext_vector_type(8))) _Float16 half8;
typedef __attribute__((ext_vector_type(4))) float f32x4;
typedef __attribute__((ext_vector_type(16))) float f32x16;
typedef unsigned short u16;

#define GLB_CAST(p) ((const __attribute__((address_space(1))) void*)(p))
#define LDS_CAST(p) ((__attribute__((address_space(3))) void*)(p))

static __device__ __forceinline__ void gload_lds16(const void* g, void* l) {
  __builtin_amdgcn_global_load_lds(GLB_CAST(g), LDS_CAST(l), 16, 0, 0);
}
static __device__ __forceinline__ u16 f2h(float f) {
  _Float16 h = (_Float16)f;
  return __builtin_bit_cast(u16, h);
}
static __device__ __forceinline__ float h2f(u16 u) {
  _Float16 h = __builtin_bit_cast(_Float16, u);
  return (float)h;
}

// ---------------------------------------------------------------------------
// Tiled transpose + f32 -> f16:  dst[j*dst_ld + k] = f16(src[k*src_ld + j0 + j])
// ---------------------------------------------------------------------------
__global__ __launch_bounds__(256) void transpose_conv(
    const float* __restrict__ src, int src_ld, int j0,
    u16* __restrict__ dst, int dst_ld)
{
  __shared__ float tile[32][33];
  const int kt = blockIdx.y * 32, jt = blockIdx.x * 32;
  const int tr = threadIdx.x >> 5, tc = threadIdx.x & 31;
#pragma unroll
  for (int r = 0; r < 4; r++)
    tile[tr + r * 8][tc] = src[(size_t)(kt + tr + r * 8) * src_ld + j0 + jt + tc];
  __syncthreads();
#pragma unroll
  for (int r = 0; r < 4; r++)
    dst[(size_t)(jt + tr + r * 8) * dst_ld + kt + tc] = f2h(tile[tc][tr + r * 8]);
}

__global__ __launch_bounds__(256) void convert_f2h(
    const float* __restrict__ src, u16* __restrict__ dst)
{
  const int i = (blockIdx.x * 256 + threadIdx.x) * 4;
  float4 v = *(const float4*)(src + i);
  dst[i + 0] = f2h(v.x); dst[i + 1] = f2h(v.y);
  dst[i + 2] = f2h(v.z); dst[i + 3] = f2h(v.w);
}

// bconst[j] = b_x[j] + sum_k b_d[k] * XT[j][k]
__global__ __launch_bounds__(256) void bconst_kernel(
    const float* __restrict__ bx, const float* __restrict__ bd,
    const u16* __restrict__ XT, float* __restrict__ bc)
{
  __shared__ float sbd[1024];
  const int tid = threadIdx.x;
  for (int i = tid; i < 1024; i += 256) sbd[i] = bd[i];
  __syncthreads();
  const int j = blockIdx.x * 256 + tid;
  const u16* row = XT + (size_t)j * 1024;
  float s = bx[j];
  for (int k = 0; k < 1024; k += 8) {
    half8 v = *(const half8*)(row + k);
#pragma unroll
    for (int u = 0; u < 8; u++) s += sbd[k + u] * (float)v[u];
  }
  bc[j] = s;
}

// ---------------------------------------------------------------------------
// gemm_wc: WC[m][n] = sum_k XT[m][k]*Wd16[n][k] (+HT[m][n] for m<4096), f16 out
// 128x128 tile, 512 thr (8 waves = 4rw x 2jw), 2-buf counted-vmcnt pipeline.
// grid (48, 16) m-fastest.  K = 1024.
// ---------------------------------------------------------------------------
__global__ __launch_bounds__(512) void gemm_wc(
    const u16* __restrict__ A, const u16* __restrict__ Bm,
    const u16* __restrict__ HT, u16* __restrict__ Cw)
{
  __shared__ __attribute__((aligned(16))) u16 a_lds[2][128 * 64];
  __shared__ __attribute__((aligned(16))) u16 b_lds[2][128 * 64];
  const int tid = threadIdx.x, w = tid >> 6, l = tid & 63;
  const int rw = w >> 1, jw = w & 1;
  const int m0 = blockIdx.x * 128, n0 = blockIdx.y * 128;
  f32x4 acc[2][4] = {};

  const u16 *asrc[2], *bsrc[2];
#pragma unroll
  for (int rnd = 0; rnd < 2; rnd++) {
    int flat = rnd * 512 + tid;
    int row = flat >> 3, gch = (flat & 7) ^ (row & 7);
    asrc[rnd] = A + (size_t)(m0 + row) * 1024 + gch * 8;
    bsrc[rnd] = Bm + (size_t)(n0 + row) * 1024 + gch * 8;
  }
  auto stage = [&](int buf, int kk) {   // 4 gloads/thread
#pragma unroll
    for (int rnd = 0; rnd < 2; rnd++) {
      int flat = rnd * 512 + tid;
      gload_lds16(asrc[rnd] + kk, a_lds[buf] + flat * 8);
      gload_lds16(bsrc[rnd] + kk, b_lds[buf] + flat * 8);
    }
  };
  auto compute = [&](int buf) {
    __builtin_amdgcn_s_setprio(1);
#pragma unroll
    for (int kh = 0; kh < 2; kh++) {
      const int c = kh * 4 + (l >> 4);
      half8 a[2], b[4];
#pragma unroll
      for (int mf = 0; mf < 2; mf++) {
        int arow = rw * 32 + mf * 16 + (l & 15);
        a[mf] = *(const half8*)(a_lds[buf] + (arow * 8 + (c ^ (arow & 7))) * 8);
      }
#pragma unroll
      for (int nf = 0; nf < 4; nf++) {
        int brow = jw * 64 + nf * 16 + (l & 15);
        b[nf] = *(const half8*)(b_lds[buf] + (brow * 8 + (c ^ (brow & 7))) * 8);
      }
#pragma unroll
      for (int mf = 0; mf < 2; mf++)
#pragma unroll
        for (int nf = 0; nf < 4; nf++)
          acc[mf][nf] = __builtin_amdgcn_mfma_f32_16x16x32_f16(a[mf], b[nf], acc[mf][nf], 0, 0, 0);
    }
    __builtin_amdgcn_s_setprio(0);
  };

  stage(0, 0);
#pragma unroll 1
  for (int t = 0; t < 16; ++t) {
    if (t < 15) {
      stage((t + 1) & 1, (t + 1) * 64);
      asm volatile("s_waitcnt vmcnt(4)\ns_barrier" ::: "memory");
    } else {
      asm volatile("s_waitcnt vmcnt(0)\ns_barrier" ::: "memory");
    }
    compute(t & 1);
    asm volatile("s_barrier" ::: "memory");
  }

#pragma unroll
  for (int mf = 0; mf < 2; mf++)
#pragma unroll
    for (int nf = 0; nf < 4; nf++) {
      const int n = n0 + jw * 64 + nf * 16 + (l & 15);
#pragma unroll
      for (int i = 0; i < 4; i++) {
        const int m = m0 + rw * 32 + mf * 16 + (l >> 4) * 4 + i;
        float v = acc[mf][nf][i];
        if (m < 4096) v += h2f(HT[(size_t)m * 2048 + n]);
        Cw[(size_t)m * 2048 + n] = f2h(v);
      }
    }
}

// ---------------------------------------------------------------------------
// gemm_out: O[m][n] = sum_k Hs[m][k]*DT[n][k] + bd[n]; fused BN partial stats.
// 128x128 tile, 256 thr (4 waves = 2mw x 2nw, 64x64 wave tiles, 32x32x16),
// 2-buf counted-vmcnt, 64KB LDS -> 2 blocks/CU.  grid (64, 8) m-fastest.
// ---------------------------------------------------------------------------
__global__ __launch_bounds__(256) void gemm_out(
    const u16* __restrict__ A, const u16* __restrict__ Bm,
    const float* __restrict__ bd, float* __restrict__ O,
    float* __restrict__ bnsum, float* __restrict__ bnsq)
{
  __shared__ __attribute__((aligned(16))) u16 a_lds[2][128 * 64];  // 16KB each
  __shared__ __attribute__((aligned(16))) u16 b_lds[2][128 * 64];
  const int tid = threadIdx.x, w = tid >> 6, l = tid & 63;
  const int mw = w >> 1, nw = w & 1;
  const int m0 = blockIdx.x * 128, n0 = blockIdx.y * 128;
  const int lr = l & 31, lh = l >> 5;
  f32x16 acc[2][2] = {};

  const u16 *asrc[4], *bsrc[4];
#pragma unroll
  for (int rnd = 0; rnd < 4; rnd++) {
    int flat = rnd * 256 + tid;
    int row = flat >> 3, gch = (flat & 7) ^ (row & 7);
    asrc[rnd] = A + (size_t)(m0 + row) * 2048 + gch * 8;
    bsrc[rnd] = Bm + (size_t)(n0 + row) * 2048 + gch * 8;
  }
  auto stage = [&](int buf, int kk) {  // 8 gloads/thread
#pragma unroll
    for (int rnd = 0; rnd < 4; rnd++) {
      gload_lds16(asrc[rnd] + kk, a_lds[buf] + (rnd * 256 + tid) * 8);
      gload_lds16(bsrc[rnd] + kk, b_lds[buf] + (rnd * 256 + tid) * 8);
    }
  };
  auto compute = [&](int buf) {
    __builtin_amdgcn_s_setprio(1);
#pragma unroll
    for (int ks = 0; ks < 4; ks++) {       // four K16 slices of the K64 step
      const int c = ks * 2 + lh;
      half8 a[2], b[2];
#pragma unroll
      for (int mf = 0; mf < 2; mf++) {
        int ar = mw * 64 + mf * 32 + lr;
        a[mf] = *(const half8*)(a_lds[buf] + (ar * 8 + (c ^ (ar & 7))) * 8);
      }
#pragma unroll
      for (int nf = 0; nf < 2; nf++) {
        int br = nw * 64 + nf * 32 + lr;
        b[nf] = *(const half8*)(b_lds[buf] + (br * 8 + (c ^ (br & 7))) * 8);
      }
#pragma unroll
      for (int mf = 0; mf < 2; mf++)
#pragma unroll
        for (int nf = 0; nf < 2; nf++)
          acc[mf][nf] = __builtin_amdgcn_mfma_f32_32x32x16_f16(a[mf], b[nf], acc[mf][nf], 0, 0, 0);
    }
    __builtin_amdgcn_s_setprio(0);
  };

  stage(0, 0);
#pragma unroll 1
  for (int t = 0; t < 32; ++t) {
    if (t < 31) {
      stage((t + 1) & 1, (t + 1) * 64);
      asm volatile("s_waitcnt vmcnt(8)\ns_barrier" ::: "memory");
    } else {
      asm volatile("s_waitcnt vmcnt(0)\ns_barrier" ::: "memory");
    }
    compute(t & 1);
    asm volatile("s_barrier" ::: "memory");
  }

  // epilogue: C/D row within 32 = (reg&3) + 8*(reg>>2) + 4*lh, col = lr
  const int fr = m0 >> 8;   // frame index (2 m-tiles per frame)
#pragma unroll
  for (int nf = 0; nf < 2; nf++) {
    const int n = n0 + nw * 64 + nf * 32 + lr;
    const float bb = bd[n];
    float s = 0.f, q = 0.f;
#pragma unroll
    for (int mf = 0; mf < 2; mf++)
#pragma unroll
      for (int reg = 0; reg < 16; reg++) {
        const int m = m0 + mw * 64 + mf * 32 + (reg & 3) + 8 * (reg >> 2) + 4 * lh;
        float v = acc[mf][nf][reg] + bb;
        O[(size_t)m * 1024 + n] = v;
        s += v; q += v * v;
      }
    s += __shfl_xor(s, 32, 64); q += __shfl_xor(q, 32, 64);
    if (lh == 0) {
      atomicAdd(&bnsum[fr * 1024 + n], s);
      atomicAdd(&bnsq[fr * 1024 + n], q);
    }
  }
}

// ---------------------------------------------------------------------------
// Frame 0: gates from x @ W_x only (h=0).  grid (64,4), 512 thr, dbuf.
// ---------------------------------------------------------------------------
__global__ __launch_bounds__(512) void frame0_kernel(
    const u16* __restrict__ x16, const u16* __restrict__ XT,
    const float* __restrict__ bx, const float* __restrict__ bh,
    float* __restrict__ h32out, u16* __restrict__ hout16)
{
  __shared__ __attribute__((aligned(16))) u16 a_lds[2][64 * 64];
  __shared__ __attribute__((aligned(16))) u16 b_lds[2][96 * 64];
  const int tid = threadIdx.x, w = tid >> 6, l = tid & 63;
  const int rw = w >> 1, jw = w & 1;
  const int jt = blockIdx.x, r0 = blockIdx.y * 64;
  f32x4 acc[3] = {};

  const int ar = tid >> 3;
  const int agch = (tid & 7) ^ (ar & 7);
  const u16* asrc = x16 + (size_t)(r0 + ar) * 1024 + agch * 8;
  const u16* bsrc0;
  const u16* bsrc1;
  {
    int row0 = tid >> 3, gch0 = (tid & 7) ^ (row0 & 7);
    bsrc0 = XT + (size_t)((row0 >> 5) * 2048 + jt * 32 + (row0 & 31)) * 1024 + gch0 * 8;
    int flat = 512 + tid;
    int row1 = flat >> 3, gch1 = (flat & 7) ^ (row1 & 7);
    bsrc1 = XT + (size_t)((row1 >> 5) * 2048 + jt * 32 + (row1 & 31)) * 1024 + gch1 * 8;
  }
  auto stage = [&](int buf, int kk) {
    gload_lds16(asrc + kk, a_lds[buf] + tid * 8);
    gload_lds16(bsrc0 + kk, b_lds[buf] + tid * 8);
    if (512 + tid < 768)
      gload_lds16(bsrc1 + kk, b_lds[buf] + (512 + tid) * 8);
  };

  stage(0, 0);
  __syncthreads();
  int cur = 0;
  for (int t = 0; t < 16; ++t) {
    if (t < 15) stage(cur ^ 1, (t + 1) * 64);
    const int arow = rw * 16 + (l & 15);
#pragma unroll
    for (int kh = 0; kh < 2; kh++) {
      int apch = (kh * 4 + (l >> 4)) ^ (arow & 7);
      half8 a = *(const half8*)(a_lds[cur] + arow * 64 + apch * 8);
#pragma unroll
      for (int s = 0; s < 3; s++) {
        int brow = s * 32 + jw * 16 + (l & 15);
        int bpch = (kh * 4 + (l >> 4)) ^ (brow & 7);
        half8 bf = *(const half8*)(b_lds[cur] + brow * 64 + bpch * 8);
        acc[s] = __builtin_amdgcn_mfma_f32_16x16x32_f16(a, bf, acc[s], 0, 0, 0);
      }
    }
    __syncthreads();
    cur ^= 1;
  }

  const int j = jt * 32 + jw * 16 + (l & 15);
  const float cR = bx[j] + bh[j];
  const float cZ = bx[2048 + j] + bh[2048 + j];
  const float cX = bx[4096 + j];
  const float hn0 = bh[4096 + j];
#pragma unroll
  for (int i = 0; i < 4; i++) {
    const int b = r0 + rw * 16 + (l >> 4) * 4 + i;
    float r = 1.f / (1.f + __expf(-(acc[0][i] + cR)));
    float z = 1.f / (1.f + __expf(-(acc[1][i] + cZ)));
    float n = tanhf(acc[2][i] + cX + r * hn0);
    float hv = (1.f - z) * n;
    h32out[b * 2048 + j] = hv;
    hout16[b * 2048 + j] = f2h(hv);
  }
}

// ---------------------------------------------------------------------------
// Frames 1..31: gates = h @ WC^T (+consts), GRU update.
// grid (64,4), 512 thr = 8 waves = 2cw x 4kw.  Wave tile 64x64 (2mf x 2nf,
// mfma 32x32x16); kw = K16-slice of each K64 step.  4-buf counted-vmcnt
// depth-2 pipeline.  Per step/wave: 4 ds_read + 4 MFMA.
// End: 4-way kw reduction via 128KB LDS exchange + GRU epilogue.
// C/D: col = l&31, row = (reg&3)+8*(reg>>2)+4*(l>>5)  [m74/m101].
// ---------------------------------------------------------------------------
__global__ __launch_bounds__(512) void frame_kernel(
    const u16* __restrict__ hin16,   // Hs[t-1]  [256][2048]
    const u16* __restrict__ WC,      // [8192][2048]
    const float* __restrict__ bc, const float* __restrict__ bh,
    const float* __restrict__ h32in, float* __restrict__ h32out,
    u16* __restrict__ hout16)        // Hs[t]
{
  __shared__ __attribute__((aligned(16))) char raw[131072];  // 128 KB
  u16* aL = (u16*)raw;                  // 4 bufs x 8KB
  u16* bL = (u16*)(raw + 32768);        // 4 bufs x 16KB
  float* xch = (float*)raw;             // reduction exchange (aliased)
  const int tid = threadIdx.x, w = tid >> 6, l = tid & 63;
  const int cw = w & 1, kw = w >> 1;    // col-half, K16 slice
  const int jt = blockIdx.x, r0 = blockIdx.y * 64;
  const int lr = l & 31, lh = l >> 5;

  f32x16 acc[2][2] = {};                // [mf][nf]

  const u16* asrc;                      // 1 load/thread
  {
    int row = tid >> 3, gch = (tid & 7) ^ (row & 7);
    asrc = hin16 + (size_t)(r0 + row) * 2048 + gch * 8;
  }
  const u16* bsrc[2];                   // 2 loads/thread
#pragma unroll
  for (int rnd = 0; rnd < 2; rnd++) {
    int flat = rnd * 512 + tid;
    int row = flat >> 3, gch = (flat & 7) ^ (row & 7);
    int sec = row >> 5, jr = row & 31;
    bsrc[rnd] = WC + (size_t)(sec * 2048 + jt * 32 + jr) * 2048 + gch * 8;
  }
  auto stage = [&](int buf, int step) {   // 3 gloads/thread
    const int kk = step * 64;
    gload_lds16(asrc + kk, aL + buf * 4096 + tid * 8);
    gload_lds16(bsrc[0] + kk, bL + buf * 8192 + tid * 8);
    gload_lds16(bsrc[1] + kk, bL + buf * 8192 + (512 + tid) * 8);
  };
  auto compute = [&](int buf) {
    half8 a[2], b[2];
    const int c = kw * 2 + lh;          // chunk 0..7 within K64
#pragma unroll
    for (int mf = 0; mf < 2; mf++) {
      int ar2 = mf * 32 + lr;
      a[mf] = *(const half8*)(aL + buf * 4096 + (ar2 * 8 + (c ^ (ar2 & 7))) * 8);
    }
#pragma unroll
    for (int nf = 0; nf < 2; nf++) {
      int br = (cw * 2 + nf) * 32 + lr;
      b[nf] = *(const half8*)(bL + buf * 8192 + (br * 8 + (c ^ (br & 7))) * 8);
    }
    __builtin_amdgcn_s_setprio(1);
#pragma unroll
    for (int mf = 0; mf < 2; mf++)
#pragma unroll
      for (int nf = 0; nf < 2; nf++)
        acc[mf][nf] = __builtin_amdgcn_mfma_f32_32x32x16_f16(a[mf], b[nf], acc[mf][nf], 0, 0, 0);
    __builtin_amdgcn_s_setprio(0);
  };

  stage(0, 0);
  stage(1, 1);
#pragma unroll 1
  for (int t = 0; t < 30; ++t) {
    stage((t + 2) & 3, t + 2);
    asm volatile("s_waitcnt vmcnt(6)\ns_barrier" ::: "memory");
    compute(t & 3);
  }
  asm volatile("s_waitcnt vmcnt(3)\ns_barrier" ::: "memory");
  compute(2);
  asm volatile("s_waitcnt vmcnt(0)\ns_barrier" ::: "memory");
  compute(3);

  // ---- 4-way kw reduction via LDS exchange ----
  __syncthreads();   // drain all LDS reads before aliasing bufs as xch
#pragma unroll
  for (int mf = 0; mf < 2; mf++)
#pragma unroll
    for (int nf = 0; nf < 2; nf++)
#pragma unroll
      for (int q = 0; q < 4; q++) {
        f32x4 v;
#pragma unroll
        for (int d = 0; d < 4; d++) v[d] = acc[mf][nf][q * 4 + d];
        *(f32x4*)(xch + (cw * 4 + kw) * 4096 +
                  (((mf * 2 + nf) * 4 + q) * 64 + l) * 4) = v;
      }
  __syncthreads();

  // reducer wave w: mf2 = w>>2, q2 = w&3; owns rows mf2*32 + 8*q2 + 4*lh + d
  const int mf2 = w >> 2, q2 = w & 3;
  f32x4 g[4];   // R, Z, Xn, Hn summed over the 4 kw partials
#pragma unroll
  for (int sec = 0; sec < 4; sec++) {
    f32x4 s = {};
#pragma unroll
    for (int k2 = 0; k2 < 4; k2++)
      s += *(const f32x4*)(xch + ((sec >> 1) * 4 + k2) * 4096 +
                           (((mf2 * 2 + (sec & 1)) * 4 + q2) * 64 + l) * 4);
    g[sec] = s;
  }
  const int j = jt * 32 + lr;
  const float cR = bc[j] + bh[j];
  const float cZ = bc[2048 + j] + bh[2048 + j];
  const float cX = bc[4096 + j];
  const float cH = bh[4096 + j];
#pragma unroll
  for (int d = 0; d < 4; d++) {
    const int bb = r0 + mf2 * 32 + 8 * q2 + 4 * lh + d;
    float rg = 1.f / (1.f + __expf(-(g[0][d] + cR)));
    float zg = 1.f / (1.f + __expf(-(g[1][d] + cZ)));
    float ng = tanhf(g[2][d] + cX + rg * (g[3][d] + cH));
    float hp = h32in[bb * 2048 + j];
    float hv = (1.f - zg) * ng + zg * hp;
    h32out[bb * 2048 + j] = hv;
    hout16[bb * 2048 + j] = f2h(hv);
  }
}

// ---------------------------------------------------------------------------
// BN apply (stats precomputed): one pass over d_out.  grid (32,4), 256 thr.
// ---------------------------------------------------------------------------
__global__ __launch_bounds__(256) void bn_apply(
    float* __restrict__ O, const float* __restrict__ bnsum,
    const float* __restrict__ bnsq, const float* __restrict__ gamma,
    const float* __restrict__ beta)
{
  const int t = blockIdx.x, j = blockIdx.y * 256 + threadIdx.x;
  const float mean = bnsum[t * 1024 + j] * (1.f / 256.f);
  const float var = bnsq[t * 1024 + j] * (1.f / 256.f) - mean * mean;
  const float inv = rsqrtf(var + 1e-5f);
  const float g = gamma[j] * inv, be = beta[j];
  const size_t base = (size_t)t * 256 * 1024 + j;
  for (int b = 0; b < 256; b++) {
    const size_t idx = base + (size_t)b * 1024;
    O[idx] = (O[idx] - mean) * g + be;
  }
}

// ---------------------------------------------------------------------------
extern "C" void kernel_launch(void* const* d_in, const int* in_sizes, int n_in,
                              void* d_out, int out_size, void* d_ws, size_t ws_size,
                              hipStream_t stream)
{
  (void)in_sizes; (void)n_in; (void)out_size; (void)ws_size;
  const float* x  = (const float*)d_in[0];
  const float* Wx = (const float*)d_in[1];
  const float* Wh = (const float*)d_in[2];
  const float* bx = (const float*)d_in[3];
  const float* bh = (const float*)d_in[4];
  const float* Wd = (const float*)d_in[5];
  const float* bd = (const float*)d_in[6];
  const float* gamma = (const float*)d_in[7];
  const float* beta  = (const float*)d_in[8];

  char* p = (char*)d_ws;
  u16* XT  = (u16*)p;  p += (size_t)6144 * 1024 * 2;   // W_x^T  [6144][1024]
  u16* WC  = (u16*)p;  p += (size_t)8192 * 2048 * 2;   // combined weights
  u16* DT  = (u16*)p;  p += (size_t)1024 * 2048 * 2;   // W_d^T  [1024][2048]
  float* h32a = (float*)p; p += (size_t)256 * 2048 * 4;
  float* h32b = (float*)p; p += (size_t)256 * 2048 * 4;
  u16* x16 = (u16*)p;  p += (size_t)256 * 1024 * 2;
  float* bc = (float*)p; p += (size_t)6144 * 4;
  float* bnsum = (float*)p; p += (size_t)32 * 1024 * 4;
  float* bnsq  = (float*)p; p += (size_t)32 * 1024 * 4;
  // aliased region: HT+Wd16 (setup only) overlaid by Hs (frame0 onward)
  u16* Hs   = (u16*)p;                                  // [32][256][2048]
  u16* HT   = (u16*)p;                                  // [4096][2048]
  u16* Wd16 = (u16*)(p + (size_t)4096 * 2048 * 2);      // [2048][1024]

  const size_t BH = (size_t)256 * 2048;

  // --- setup ---------------------------------------------------------------
  transpose_conv<<<dim3(192, 32), 256, 0, stream>>>(Wx, 6144, 0, XT, 1024);
  transpose_conv<<<dim3(128, 64), 256, 0, stream>>>(Wh, 6144, 0, HT, 2048);
  transpose_conv<<<dim3(64, 64), 256, 0, stream>>>(Wh, 6144, 4096,
                                                   WC + (size_t)6144 * 2048, 2048);
  transpose_conv<<<dim3(32, 64), 256, 0, stream>>>(Wd, 1024, 0, DT, 2048);
  convert_f2h<<<2048, 256, 0, stream>>>(Wd, Wd16);
  convert_f2h<<<256, 256, 0, stream>>>(x, x16);
  bconst_kernel<<<24, 256, 0, stream>>>(bx, bd, XT, bc);
  hipMemsetAsync(bnsum, 0, (size_t)2 * 32 * 1024 * 4, stream);
  // WC[0:6144] = XT @ Wd16^T (+HT for rows<4096)
  gemm_wc<<<dim3(48, 16), 512, 0, stream>>>(XT, Wd16, HT, WC);

  // --- recurrence ----------------------------------------------------------
  frame0_kernel<<<dim3(64, 4), 512, 0, stream>>>(x16, XT, bx, bh, h32a, Hs);
  for (int t = 1; t < 32; t++) {
    const float* hin32 = (t & 1) ? h32a : h32b;
    float* hout32      = (t & 1) ? h32b : h32a;
    frame_kernel<<<dim3(64, 4), 512, 0, stream>>>(
        Hs + (size_t)(t - 1) * BH, WC, bc, bh, hin32, hout32, Hs + (size_t)t * BH);
  }

  // --- all 32 output frames in one GEMM (+BN stats), then BN apply ---------
  gemm_out<<<dim3(64, 8), 256, 0, stream>>>(Hs, DT, bd, (float*)d_out, bnsum, bnsq);
  bn_apply<<<dim3(32, 4), 256, 0, stream>>>((float*)d_out, bnsum, bnsq, gamma, beta);
}